// Round 4
// baseline (64.336 us; speedup 1.0000x reference)
//
#include <hip/hip_runtime.h>
#include <stdint.h>

#define IN_F   4096
#define OUT_F  11008
#define C32    5504     // packed dwords per k-row
#define KSPL   4        // K-split factor
#define KBLK   1024     // k per block
#define NST    16       // stages per block, 64 k each
#define NGRP   8        // scale groups per block (KBLK/128)
#define LDST   72       // ushorts per LDS col row (64 k + 8 pad; 144B, 16B-aligned)

typedef __attribute__((ext_vector_type(8))) _Float16 half8;
typedef __attribute__((ext_vector_type(4))) float floatx4;

// single-instruction f32 pair -> packed fp16 (RTZ)
static __device__ __forceinline__ uint32_t pkh(float a, float b) {
    auto h = __builtin_amdgcn_cvt_pkrtz(a, b);
    union { decltype(h) v; uint32_t u; } r; r.v = h; return r.u;
}

// Prep: zero output (atomic K-split epilogue) + convert x f32 -> fp16 pairs.
__global__ __launch_bounds__(256) void prep_kernel(
    const float* __restrict__ x, uint32_t* __restrict__ xh, float4* __restrict__ out4)
{
    int tid = blockIdx.x * 256 + threadIdx.x;
    if (tid < (64 * OUT_F / 4)) out4[tid] = make_float4(0.f, 0.f, 0.f, 0.f);
    if (tid < (64 * IN_F / 2)) {
        float2 v = ((const float2*)x)[tid];
        xh[tid] = pkh(v.x, v.y);
    }
}

// BARRIER-FREE K-loop: each wave owns 16 cols x 64 tokens x KBLK=1024 and
// stages its weight tile into a WAVE-PRIVATE LDS double buffer. Write->read
// ordering within one wave is just in-order lgkmcnt (compiler-inserted); the
// only __syncthreads is after the scale-table init. ~11 independent wave
// pipelines per CU replace ~2.7 barrier-locked block pipelines.
__global__ __launch_bounds__(256, 4) void int4_gemm_kernel(
    const int*      __restrict__ wp,      // [4096][5504] (byte in low 8 bits)
    const float*    __restrict__ wscale,  // f32 [32][11008]
    const float*    __restrict__ wzero,   // f32 [32][11008]
    const uint32_t* __restrict__ xh,      // fp16 pairs [64][2048]
    float*          __restrict__ out)     // f32 [64][11008]
{
    __shared__ float4 tab[NGRP * 32];                     // [group][colpair of 64 cols]: 4 KB
    __shared__ __align__(16) ushort bld[4][2][16 * LDST]; // per-wave dbuf: 4 x 2 x 2.25 KB

    const int tid   = threadIdx.x;
    const int wv    = tid >> 6;
    const int l     = tid & 63;
    const int col0  = blockIdx.x * 64;         // block cols
    const int wcol  = col0 + wv * 16;          // this wave's 16 cols
    const int kbase = blockIdx.y * KBLK;

    // staging role (within wave): dword-col c -> out cols 2c,2c+1; k-octet r
    const int c = l & 7;                       // 0..7
    const int r = l >> 3;                      // 0..7 -> k rows r*8 .. r*8+7
    const int* wbase = wp + (size_t)(kbase + r * 8) * C32 + (wcol >> 1) + c;

    // MFMA role
    const int g  = l >> 4;
    const int bc = l & 15;
    const uint32_t* xbase = xh + (size_t)bc * (IN_F / 2) + (kbase >> 1) + g * 4;

    // (scale, zero*scale) table: 8 groups x 32 col-pairs, 1 entry/thread
    {
        int gg = tid >> 5, cp = tid & 31;
        size_t b = (size_t)(blockIdx.y * NGRP + gg) * OUT_F + col0 + 2 * cp;
        float se = wscale[b], so = wscale[b + 1];
        float ze = wzero[b],  zo = wzero[b + 1];
        tab[tid] = make_float4(se, ze * se, so, zo * so);
    }
    __syncthreads();                           // the ONLY block barrier

    ushort* buf0 = bld[wv][0];
    ushort* buf1 = bld[wv][1];

    floatx4 acc[4] = {{0.f,0.f,0.f,0.f},{0.f,0.f,0.f,0.f},
                      {0.f,0.f,0.f,0.f},{0.f,0.f,0.f,0.f}};

    auto load8 = [&](uint32_t* w, int st) {
        const int* p = wbase + (size_t)st * (64 * (size_t)C32);
        #pragma unroll
        for (int j = 0; j < 8; ++j) w[j] = (uint32_t)p[j * C32];
    };

    auto dq_write = [&](ushort* buf, const uint32_t* w, int st) {
        float4 t = tab[((st >> 1) << 5) + wv * 8 + c];
        uint32_t lo[4], hi[4];
        #pragma unroll
        for (int j = 0; j < 4; ++j) {
            float l0 = fmaf((float)( w[2*j]        & 15u), t.x, -t.y);
            float l1 = fmaf((float)( w[2*j+1]      & 15u), t.x, -t.y);
            float h0 = fmaf((float)((w[2*j]   >> 4) & 15u), t.z, -t.w);
            float h1 = fmaf((float)((w[2*j+1] >> 4) & 15u), t.z, -t.w);
            lo[j] = pkh(l0, l1);
            hi[j] = pkh(h0, h1);
        }
        *(uint4*)(buf + (2*c)     * LDST + r*8) = *(uint4*)lo;  // col 2c,   k r*8..r*8+7
        *(uint4*)(buf + (2*c + 1) * LDST + r*8) = *(uint4*)hi;  // col 2c+1
    };

    auto compute = [&](const ushort* buf, int st) {
        half8 B0 = *(const half8*)(buf + bc * LDST + g * 8);        // k-half 0
        half8 B1 = *(const half8*)(buf + bc * LDST + 32 + g * 8);   // k-half 1
        #pragma unroll
        for (int rt = 0; rt < 4; ++rt) {
            union { uint4 u; half8 h; } a0, a1;
            a0.u = *(const uint4*)(xbase + (size_t)rt * 32768 + st * 32);
            a1.u = *(const uint4*)(xbase + (size_t)rt * 32768 + st * 32 + 16);
            acc[rt] = __builtin_amdgcn_mfma_f32_16x16x32_f16(a0.h, B0, acc[rt], 0, 0, 0);
            acc[rt] = __builtin_amdgcn_mfma_f32_16x16x32_f16(a1.h, B1, acc[rt], 0, 0, 0);
        }
    };

    // ---- per-wave pipeline: W-ring depth 2 (named sets wa/wb, static) ----
    uint32_t wa[8], wb[8];
    load8(wa, 0);
    load8(wb, 1);
    dq_write(buf0, wa, 0);
    load8(wa, 2);

    #pragma unroll 1
    for (int st = 0; st < NST; st += 2) {
        compute(buf0, st);
        dq_write(buf1, wb, st + 1);
        if (st + 3 < NST) load8(wb, st + 3);
        compute(buf1, st + 1);
        if (st + 2 < NST) {
            dq_write(buf0, wa, st + 2);
            if (st + 4 < NST) load8(wa, st + 4);
        }
    }

    // epilogue: C/D layout col = lane&15, row = (lane>>4)*4 + reg  [m89/m91]
    const int ocol = wcol + bc;
    #pragma unroll
    for (int rt = 0; rt < 4; ++rt) {
        #pragma unroll
        for (int j = 0; j < 4; ++j) {
            unsafeAtomicAdd(out + (size_t)(rt * 16 + g * 4 + j) * OUT_F + ocol, acc[rt][j]);
        }
    }
}

extern "C" void kernel_launch(void* const* d_in, const int* in_sizes, int n_in,
                              void* d_out, int out_size, void* d_ws, size_t ws_size,
                              hipStream_t stream) {
    const float* x      = (const float*)d_in[0];
    const int*   wp     = (const int*)  d_in[1];
    const float* wscale = (const float*)d_in[2];
    const float* wzero  = (const float*)d_in[3];
    float*       out    = (float*)d_out;
    uint32_t*    xh     = (uint32_t*)d_ws;   // 512 KB workspace
    (void)in_sizes; (void)n_in; (void)out_size; (void)ws_size;

    prep_kernel<<<dim3(688), dim3(256), 0, stream>>>(x, xh, (float4*)out);
    int4_gemm_kernel<<<dim3(OUT_F / 64, KSPL), dim3(256), 0, stream>>>(wp, wscale, wzero, xh, out);
}

// Round 5
// 43.311 us; speedup vs baseline: 1.4855x; 1.4855x over previous
//
#include <hip/hip_runtime.h>
#include <stdint.h>

#define IN_F   4096
#define OUT_F  11008
#define C32    5504     // packed dwords per k-row
#define KSPL   8        // K-split factor
#define KBLK   512      // k per block
#define NST    8        // stages per block, 64 k each
#define NGRPL  4        // scale groups per block (KBLK/128)
#define COLS   128      // output cols per block
#define DCOLS  64       // dword cols per block
#define LDSTR  144      // bytes per LDS col (64 k * 2B + 16B pad)

typedef __attribute__((ext_vector_type(8))) _Float16 half8;
typedef __attribute__((ext_vector_type(4))) float floatx4;

// single-instruction f32 pair -> packed fp16 (RTZ)
static __device__ __forceinline__ uint32_t pkh(float a, float b) {
    auto h = __builtin_amdgcn_cvt_pkrtz(a, b);
    union { decltype(h) v; uint32_t u; } r; r.v = h; return r.u;
}

// Prep: zero output (atomic K-split epilogue) + convert x f32 -> fp16 pairs.
__global__ __launch_bounds__(256) void prep_kernel(
    const float* __restrict__ x, uint32_t* __restrict__ xh, float4* __restrict__ out4)
{
    int tid = blockIdx.x * 256 + threadIdx.x;
    if (tid < (64 * OUT_F / 4)) out4[tid] = make_float4(0.f, 0.f, 0.f, 0.f);
    if (tid < (64 * IN_F / 2)) {
        float2 v = ((const float2*)x)[tid];
        xh[tid] = pkh(v.x, v.y);
    }
}

// 128-col tile so W loads are 256B-contiguous per k-row (uint4 per thread,
// 4 consecutive rows). This attacks the ~2 TB/s scattered-64B HBM ceiling
// every previous schedule variant hit. Structure otherwise = proven R1:
// 2-barrier counted-wait loop, ring-2 W prefetch, f32 dequant + pkh.
// LDS B[col][k] with XOR-block swizzle: blk = ((k>>3) ^ (col>>3)) & 7.
__global__ __launch_bounds__(256, 4) void int4_gemm_kernel(
    const int*      __restrict__ wp,      // [4096][5504] (byte in low 8 bits)
    const float*    __restrict__ wscale,  // f32 [32][11008]
    const float*    __restrict__ wzero,   // f32 [32][11008]
    const uint32_t* __restrict__ xh,      // fp16 pairs [64][2048]
    float*          __restrict__ out)     // f32 [64][11008]
{
    __shared__ float4 tab[NGRPL * 64];                   // [group][colpair]: 4 KB
    __shared__ __align__(16) ushort bld[2][COLS * 72];   // 2 x 18 KB, swizzled B[col][k]

    const int tid   = threadIdx.x;
    const int bx    = blockIdx.x;
    const int ky    = blockIdx.y;
    const int col0  = bx * COLS;
    const int kbase = ky * KBLK;

    // staging role: thread owns dword-cols 4c4..4c4+3 (out cols 8c4..8c4+7),
    // k-rows 4kq..4kq+3 of each 64-k stage
    const int c4 = tid & 15;
    const int kq = tid >> 4;
    const int* wbase = wp + (size_t)(kbase + kq * 4) * C32 + bx * DCOLS + c4 * 4;

    // MFMA role
    const int wv = tid >> 6;
    const int g  = (tid & 63) >> 4;
    const int bc = tid & 15;
    const uint32_t* xA = xh + (size_t)(wv * 16 + bc) * (IN_F / 2) + (kbase >> 1) + g * 4;

    // (scale, zero*scale) table: 4 groups x 64 col-pairs, 1 entry/thread
    {
        int gg = tid >> 6, cp = tid & 63;
        size_t b = (size_t)(ky * NGRPL + gg) * OUT_F + col0 + 2 * cp;
        float se = wscale[b], so = wscale[b + 1];
        float ze = wzero[b],  zo = wzero[b + 1];
        tab[gg * 64 + cp] = make_float4(se, ze * se, so, zo * so);
    }

    floatx4 acc[8];
    #pragma unroll
    for (int i = 0; i < 8; ++i) acc[i] = floatx4{0.f, 0.f, 0.f, 0.f};

    struct WSet { uint4 w[4]; };
    auto issue = [&](int st) {
        const int* p = wbase + (size_t)(st * 64) * C32;
        WSet S;
        #pragma unroll
        for (int j = 0; j < 4; ++j)
            S.w[j] = *(const uint4*)(p + (size_t)j * C32);   // 16B, 256B/row segments
        return S;
    };

    // per-thread LDS write bases: col = 8c4+2d(+1), k0 = 4kq
    // laddr(col,k) = col*144 + (((k>>3) ^ (col>>3)) & 7)*16 + (k&7)*2
    const int wblk = (((kq >> 1) ^ (c4 & 7)) & 7) * 16 + (kq & 1) * 8;

    auto dq_write = [&](ushort* buf, const WSet& S, int st) {
        #pragma unroll
        for (int d = 0; d < 4; ++d) {
            float4 t = tab[(st >> 1) * 64 + 4 * c4 + d];
            float e[4], o[4];
            #pragma unroll
            for (int j = 0; j < 4; ++j) {
                uint32_t q = ((const uint32_t*)&S.w[j])[d];
                e[j] = fmaf((float)( q       & 15u), t.x, -t.y);
                o[j] = fmaf((float)((q >> 4) & 15u), t.z, -t.w);
            }
            const int ce = 8 * c4 + 2 * d;
            *(uint2*)((char*)buf + ce * LDSTR       + wblk) = make_uint2(pkh(e[0], e[1]), pkh(e[2], e[3]));
            *(uint2*)((char*)buf + (ce + 1) * LDSTR + wblk) = make_uint2(pkh(o[0], o[1]), pkh(o[2], o[3]));
        }
    };

    auto compute = [&](const ushort* buf, int st) {
        union { uint4 u; half8 h; } A0, A1;
        A0.u = *(const uint4*)(xA + st * 32);        // k-half 0 (8 fp16)
        A1.u = *(const uint4*)(xA + st * 32 + 16);   // k-half 1
        #pragma unroll
        for (int sc = 0; sc < 8; ++sc) {
            const int col = sc * 16 + bc;
            const char* cb = (const char*)buf + col * LDSTR;
            const int xr = (col >> 3) & 7;
            half8 B0 = *(const half8*)(cb + (( g      ^ xr) & 7) * 16);  // k = g*8..+7
            half8 B1 = *(const half8*)(cb + (((4 + g) ^ xr) & 7) * 16);  // k = 32+g*8..+7
            acc[sc] = __builtin_amdgcn_mfma_f32_16x16x32_f16(A0.h, B0, acc[sc], 0, 0, 0);
            acc[sc] = __builtin_amdgcn_mfma_f32_16x16x32_f16(A1.h, B1, acc[sc], 0, 0, 0);
        }
    };

    // ---- prologue: ring-2 (Pa = even stages, Pb = odd stages) ----
    WSet Pa = issue(0);
    WSet Pb = issue(1);
    __syncthreads();                          // tab ready (one-time full drain)
    dq_write(bld[0], Pa, 0);                  // counted vmcnt: waits Pa only
    Pa = issue(2);
    asm volatile("s_waitcnt lgkmcnt(0)");
    __builtin_amdgcn_s_barrier();             // bld[0] ready; Pb/Pa stay in flight

    #pragma unroll 2
    for (int st = 0; st < NST; ++st) {
        if (st + 1 < NST) {
            if ((st & 1) == 0) { dq_write(bld[(st + 1) & 1], Pb, st + 1); if (st + 3 < NST) Pb = issue(st + 3); }
            else               { dq_write(bld[(st + 1) & 1], Pa, st + 1); if (st + 3 < NST) Pa = issue(st + 3); }
        }
        compute(bld[st & 1], st);
        asm volatile("s_waitcnt lgkmcnt(0)"); // LDS ops done; vmcnt NOT drained
        __builtin_amdgcn_s_barrier();
    }

    // epilogue: C/D layout col = lane&15, row = (lane>>4)*4 + reg  [m89/m91]
    const int ocol = col0 + bc;
    const int orow = wv * 16 + g * 4;
    #pragma unroll
    for (int sc = 0; sc < 8; ++sc) {
        #pragma unroll
        for (int r = 0; r < 4; ++r) {
            unsafeAtomicAdd(out + (size_t)(orow + r) * OUT_F + ocol + sc * 16, acc[sc][r]);
        }
    }
}

extern "C" void kernel_launch(void* const* d_in, const int* in_sizes, int n_in,
                              void* d_out, int out_size, void* d_ws, size_t ws_size,
                              hipStream_t stream) {
    const float* x      = (const float*)d_in[0];
    const int*   wp     = (const int*)  d_in[1];
    const float* wscale = (const float*)d_in[2];
    const float* wzero  = (const float*)d_in[3];
    float*       out    = (float*)d_out;
    uint32_t*    xh     = (uint32_t*)d_ws;   // 512 KB workspace
    (void)in_sizes; (void)n_in; (void)out_size; (void)ws_size;

    prep_kernel<<<dim3(688), dim3(256), 0, stream>>>(x, xh, (float4*)out);
    int4_gemm_kernel<<<dim3(OUT_F / COLS, KSPL), dim3(256), 0, stream>>>(wp, wscale, wzero, xh, out);
}